// Round 10
// baseline (218.312 us; speedup 1.0000x reference)
//
#include <hip/hip_runtime.h>

#define NF 64      // hidden width (both layers)
#define NBLK 128   // chunks for the two-pass bucket sort
#define MAXNB 2048 // max buckets supported by LDS histograms (n <= 131072)

typedef unsigned short ushort_t;

__device__ inline ushort_t f2bf(float f) {               // RNE f32 -> bf16
    unsigned u = __float_as_uint(f);
    return (ushort_t)((u + 0x7fffu + ((u >> 16) & 1u)) >> 16);
}
__device__ inline float bfhi(unsigned x) { return __uint_as_float(x & 0xffff0000u); }
__device__ inline float bflo(unsigned x) { return __uint_as_float(x << 16); }

// =================== scan utilities ===================

__device__ inline int wave_incl_scan(int x, int lane) {
#pragma unroll
    for (int o = 1; o < 64; o <<= 1) { int y = __shfl_up(x, o, 64); if (lane >= o) x += y; }
    return x;
}

// 1024 elements per block (256 threads x 4); in-place safe
__global__ __launch_bounds__(256) void k_scan_a(const int* __restrict__ in, int* __restrict__ out,
                                                int* __restrict__ bsums, int n) {
    int t = threadIdx.x, lane = t & 63, wv = t >> 6;
    int base = blockIdx.x * 1024 + t * 4;
    int v[4]; int s = 0;
#pragma unroll
    for (int k = 0; k < 4; ++k) { int i = base + k; int x = (i < n) ? in[i] : 0; v[k] = s; s += x; }
    int incl = wave_incl_scan(s, lane);
    __shared__ int ws[4];
    if (lane == 63) ws[wv] = incl;
    __syncthreads();
    int wofs = 0;
#pragma unroll
    for (int w = 0; w < 4; ++w) if (w < wv) wofs += ws[w];
    int texcl = wofs + incl - s;
#pragma unroll
    for (int k = 0; k < 4; ++k) { int i = base + k; if (i < n) out[i] = texcl + v[k]; }
    if (t == 255) bsums[blockIdx.x] = wofs + incl;
}

// single-block exclusive scan over up to 2048 entries; in-place safe
__global__ __launch_bounds__(256) void k_scan_small(const int* __restrict__ cnt, int* __restrict__ ptr, int NB) {
    int t = threadIdx.x, lane = t & 63, wv = t >> 6;
    int base = t * 8;
    int local[8]; int s = 0;
#pragma unroll
    for (int k = 0; k < 8; ++k) { int i = base + k; int x = (i < NB) ? cnt[i] : 0; local[k] = s; s += x; }
    int incl = wave_incl_scan(s, lane);
    __shared__ int ws[4];
    if (lane == 63) ws[wv] = incl;
    __syncthreads();
    int wofs = 0;
#pragma unroll
    for (int w = 0; w < 4; ++w) if (w < wv) wofs += ws[w];
    int texcl = wofs + incl - s;
#pragma unroll
    for (int k = 0; k < 8; ++k) { int i = base + k; if (i < NB) ptr[i] = texcl + local[k]; }
}

// add block sums; also emit bucket pointers (bptr[b] = scanned hmat[b*NBLK], bptr[NB] = E)
__global__ __launch_bounds__(256) void k_scan_addb(int* __restrict__ data, const int* __restrict__ bsums,
                                                   int* __restrict__ bptr, int ntot, int E) {
    int i = blockIdx.x * 256 + threadIdx.x;
    if (i < ntot) {
        int v = data[i] + bsums[i >> 10];
        data[i] = v;
        if ((i & (NBLK - 1)) == 0) bptr[i / NBLK] = v;
    }
    if (i == 0) bptr[ntot / NBLK] = E;
}

// =================== contention-free bucket sort (bucket = dst >> 6) ===================

__global__ __launch_bounds__(256) void k_histA(const int* __restrict__ dst, int* __restrict__ hmat,
                                               int E, int NB, int chunk) {
    __shared__ int h[MAXNB];
    int blk = blockIdx.x;
    for (int i = threadIdx.x; i < NB; i += 256) h[i] = 0;
    __syncthreads();
    int beg = blk * chunk, end = beg + chunk; if (end > E) end = E;
    for (int e = beg + threadIdx.x; e < end; e += 256) atomicAdd(&h[dst[e] >> 6], 1);
    __syncthreads();
    for (int i = threadIdx.x; i < NB; i += 256) hmat[i * NBLK + blk] = h[i];
}

__global__ __launch_bounds__(256) void k_placeB(const int* __restrict__ src, const int* __restrict__ dst,
                                                const int* __restrict__ hmat, int* __restrict__ pairs,
                                                int E, int NB, int chunk) {
    __shared__ int cur[MAXNB];
    int blk = blockIdx.x;
    for (int i = threadIdx.x; i < NB; i += 256) cur[i] = hmat[i * NBLK + blk];
    __syncthreads();
    int beg = blk * chunk, end = beg + chunk; if (end > E) end = E;
    for (int e = beg + threadIdx.x; e < end; e += 256) {
        int s = src[e], d = dst[e];
        int off = atomicAdd(&cur[d >> 6], 1);
        pairs[off] = (s << 6) | (d & 63);
    }
}

// =================== fused node-level CSR: hist + 64-scan + row_ptr/cnt/dinv + place ===================
__global__ __launch_bounds__(256) void k_csr(const int* __restrict__ bptr, const int* __restrict__ pairs,
                                             int* __restrict__ row_ptr, int* __restrict__ cnt,
                                             float* __restrict__ dinv, int* __restrict__ col, int n) {
    __shared__ int h[64];
    __shared__ int cur[64];
    int b = blockIdx.x, t = threadIdx.x;
    if (t < 64) h[t] = 0;
    __syncthreads();
    int beg = bptr[b], end = bptr[b + 1];
    for (int j = beg + t; j < end; j += 256) atomicAdd(&h[pairs[j] & 63], 1);
    __syncthreads();
    if (t < 64) {
        int c = h[t];
        int ex = wave_incl_scan(c, t) - c;
        int node = (b << 6) + t;
        if (node < n) {
            row_ptr[node] = beg + ex;
            cnt[node] = c;
            dinv[node] = rsqrtf(1.0f + (float)c);
        }
        cur[t] = beg + ex;
    }
    __syncthreads();
    for (int j = beg + t; j < end; j += 256) {
        int pk = pairs[j];
        int p = atomicAdd(&cur[pk & 63], 1);
        col[p] = pk >> 6;
    }
}

// =================== register-blocked GEMM, no LDS (occupancy-tuned) ===================
// hs[n][64](bf16) = (X @ W) * dinv[row].  Block: 64 rows x 64 cols. Thread: 4 rows x 4 cols.
// W read straight from global: per wave each w-row is one coalesced 256 B load, L1/L2-resident
// (W <= 32 KB, reused by every block). x loads are 16-lane same-address broadcasts.
// No LDS -> no 64 KB/CU LDS cap; launch_bounds(256,8) pins VGPR <= 64 for 8 waves/SIMD.
template<int K>
__global__ __launch_bounds__(256, 8) void k_gemm(
    const float* __restrict__ X, const float* __restrict__ W,
    const float* __restrict__ dinv, ushort_t* __restrict__ out, int n)
{
    int t = threadIdx.x;
    int c0 = (t & 15) * 4;                       // 16 col-groups x 4 cols
    int row0 = blockIdx.x * 64 + (t >> 4) * 4;   // 16 row-groups x 4 rows

    const float* Xr[4];
#pragma unroll
    for (int r = 0; r < 4; ++r) {
        int row = row0 + r; if (row >= n) row = n - 1;   // clamp: dup loads, stores guarded
        Xr[r] = X + (size_t)row * K;
    }
    const float* Wc = W + c0;

    float4 acc[4];
#pragma unroll
    for (int r = 0; r < 4; ++r) acc[r] = make_float4(0.f, 0.f, 0.f, 0.f);

#pragma unroll 2
    for (int k0 = 0; k0 < K; k0 += 4) {
        float4 xv[4];
#pragma unroll
        for (int r = 0; r < 4; ++r) xv[r] = *(const float4*)(Xr[r] + k0);
        float4 w0 = *(const float4*)(Wc + (k0 + 0) * NF);
        float4 w1 = *(const float4*)(Wc + (k0 + 1) * NF);
        float4 w2 = *(const float4*)(Wc + (k0 + 2) * NF);
        float4 w3 = *(const float4*)(Wc + (k0 + 3) * NF);
#pragma unroll
        for (int r = 0; r < 4; ++r) {
            acc[r].x = fmaf(xv[r].x, w0.x, acc[r].x); acc[r].y = fmaf(xv[r].x, w0.y, acc[r].y);
            acc[r].z = fmaf(xv[r].x, w0.z, acc[r].z); acc[r].w = fmaf(xv[r].x, w0.w, acc[r].w);
            acc[r].x = fmaf(xv[r].y, w1.x, acc[r].x); acc[r].y = fmaf(xv[r].y, w1.y, acc[r].y);
            acc[r].z = fmaf(xv[r].y, w1.z, acc[r].z); acc[r].w = fmaf(xv[r].y, w1.w, acc[r].w);
            acc[r].x = fmaf(xv[r].z, w2.x, acc[r].x); acc[r].y = fmaf(xv[r].z, w2.y, acc[r].y);
            acc[r].z = fmaf(xv[r].z, w2.z, acc[r].z); acc[r].w = fmaf(xv[r].z, w2.w, acc[r].w);
            acc[r].x = fmaf(xv[r].w, w3.x, acc[r].x); acc[r].y = fmaf(xv[r].w, w3.y, acc[r].y);
            acc[r].z = fmaf(xv[r].w, w3.z, acc[r].z); acc[r].w = fmaf(xv[r].w, w3.w, acc[r].w);
        }
    }

#pragma unroll
    for (int r = 0; r < 4; ++r) {
        int row = row0 + r;
        if (row < n) {
            float di = dinv[row];
            ushort4 o;
            o.x = f2bf(acc[r].x * di); o.y = f2bf(acc[r].y * di);
            o.z = f2bf(acc[r].z * di); o.w = f2bf(acc[r].w * di);
            *(ushort4*)(out + (size_t)row * NF + c0) = o;
        }
    }
}

// =================== pull aggregation: one 16-lane group per dst node, bf16 rows ===================
// r = relu( dinv[d] * (hs[d] + sum_{s in N(d)} hs[s]) + bias )
// DECODE=0: write r row (f32);  DECODE=1: write out[d] = r . Wd + bd
template<bool DECODE>
__global__ __launch_bounds__(256) void k_pull(
    const ushort_t* __restrict__ hs, const float* __restrict__ dinv,
    const int* __restrict__ row_ptr, const int* __restrict__ cnt,
    const int* __restrict__ col, const float* __restrict__ bias,
    const float* __restrict__ Wd, const float* __restrict__ bd,
    float* __restrict__ outv, int n)
{
    int d = blockIdx.x * 16 + (threadIdx.x >> 4);
    if (d >= n) return;
    int lt = threadIdx.x & 15;            // lane in group
    int fo = lt << 2;                     // feature offset (4 features/lane)
    int grpbase = threadIdx.x & 48;       // group base lane within wave
    int beg = row_ptr[d], deg = cnt[d];

    // self-loop (bf16 row, 8B/lane)
    uint2 sv = *((const uint2*)(hs + (size_t)d * NF) + lt);
    float4 acc = make_float4(bflo(sv.x), bfhi(sv.x), bflo(sv.y), bfhi(sv.y));

    for (int jb = 0; jb < deg; jb += 16) {
        int m = deg - jb; if (m > 16) m = 16;
        int idx = (lt < m) ? col[beg + jb + lt] : 0;
        uint2 v[16];
#pragma unroll
        for (int u = 0; u < 16; ++u) {
            int kk = (u < m) ? u : (m - 1);                  // clamp: dup loads hit L1
            int s = __shfl(idx, grpbase + kk, 64);
            v[u] = *((const uint2*)(hs + (size_t)s * NF) + lt);
        }
#pragma unroll
        for (int u = 0; u < 16; ++u) {
            if (u < m) {
                acc.x += bflo(v[u].x); acc.y += bfhi(v[u].x);
                acc.z += bflo(v[u].y); acc.w += bfhi(v[u].y);
            }
        }
    }

    float di = dinv[d];
    float4 bv = *(const float4*)(bias + fo);
    float rx = fmaxf(fmaf(acc.x, di, bv.x), 0.0f);
    float ry = fmaxf(fmaf(acc.y, di, bv.y), 0.0f);
    float rz = fmaxf(fmaf(acc.z, di, bv.z), 0.0f);
    float rw = fmaxf(fmaf(acc.w, di, bv.w), 0.0f);

    if (DECODE) {
        float4 wv = *(const float4*)(Wd + fo);
        float vsum = rx * wv.x + ry * wv.y + rz * wv.z + rw * wv.w;
#pragma unroll
        for (int o = 1; o < 16; o <<= 1) vsum += __shfl_xor(vsum, o, 64);
        if (lt == 0) outv[d] = vsum + bd[0];
    } else {
        *(float4*)(outv + (size_t)d * NF + fo) = make_float4(rx, ry, rz, rw);
    }
}

extern "C" void kernel_launch(void* const* d_in, const int* in_sizes, int n_in,
                              void* d_out, int out_size, void* d_ws, size_t ws_size,
                              hipStream_t stream) {
    const float* x  = (const float*)d_in[0];
    const int*   ei = (const int*)d_in[1];
    const float* W1 = (const float*)d_in[2];
    const float* b1 = (const float*)d_in[3];
    const float* W2 = (const float*)d_in[4];
    const float* b2 = (const float*)d_in[5];
    const float* Wd = (const float*)d_in[6];
    const float* bd = (const float*)d_in[7];
    float* out = (float*)d_out;

    int n = in_sizes[0] / 128;
    int E = in_sizes[1] / 2;
    const int* src = ei;
    const int* dst = ei + E;

    int NB = (n + 63) >> 6;                 // dst buckets of 64 nodes
    int chunk = (E + NBLK - 1) / NBLK;
    int ntot = NB * NBLK;                   // hist matrix size
    int nsb = (ntot + 1023) / 1024;         // scan blocks over hmat

    // workspace layout (4-byte elems) — pairs aliases bufH region (build ends before gemm1)
    float* dinv    = (float*)d_ws;                    // n
    float* bufH    = dinv + n;                        // 64n f32 region; used as bf16 (32n f32 worth)
    float* bufA    = bufH + (size_t)n * NF;           // 64n f32
    int*   counts  = (int*)(bufA + (size_t)n * NF);   // n
    int*   row_ptr = counts + n;                      // n
    int*   col     = row_ptr + n;                     // E
    int*   hmat    = col + E;                         // NB*NBLK
    int*   bptr    = hmat + ntot;                     // NB+1
    int*   bsums   = bptr + NB + 1;                   // <=1024
    int*   pairs   = (int*)bufH;                      // E (build lifetime only)
    ushort_t* hsb  = (ushort_t*)bufH;                 // 64n bf16 (post-build lifetime)

    // ---- bucket sort by dst (contention-free) ----
    k_histA<<<NBLK, 256, 0, stream>>>(dst, hmat, E, NB, chunk);
    k_scan_a<<<nsb, 256, 0, stream>>>(hmat, hmat, bsums, ntot);
    k_scan_small<<<1, 256, 0, stream>>>(bsums, bsums, nsb);
    k_scan_addb<<<(ntot + 255) / 256, 256, 0, stream>>>(hmat, bsums, bptr, ntot, E);
    k_placeB<<<NBLK, 256, 0, stream>>>(src, dst, hmat, pairs, E, NB, chunk);

    // ---- fused node-level CSR + dinv ----
    k_csr<<<NB, 256, 0, stream>>>(bptr, pairs, row_ptr, counts, dinv, col, n);

    // ---- layer 1: hs = bf16((x @ W1) * dinv) ; pull (+b1, relu) ----  (pairs dead from here)
    k_gemm<128><<<(n + 63) / 64, 256, 0, stream>>>(x, W1, dinv, hsb, n);
    k_pull<false><<<(n + 15) / 16, 256, 0, stream>>>(hsb, dinv, row_ptr, counts, col, b1,
                                                     Wd, bd, bufA, n);

    // ---- layer 2: hs = bf16((bufA @ W2) * dinv) ; pull (+b2, relu) + fused decode ----
    k_gemm<64><<<(n + 63) / 64, 256, 0, stream>>>(bufA, W2, dinv, hsb, n);
    k_pull<true><<<(n + 15) / 16, 256, 0, stream>>>(hsb, dinv, row_ptr, counts, col, b2,
                                                    Wd, bd, out, n);
}

// Round 11
// 179.802 us; speedup vs baseline: 1.2142x; 1.2142x over previous
//
#include <hip/hip_runtime.h>

#define NF 64      // hidden width (both layers)
#define NBLK 128   // chunks for the two-pass bucket sort
#define MAXNB 2048 // max buckets supported by LDS histograms (n <= 131072)

typedef unsigned short ushort_t;

__device__ inline ushort_t f2bf(float f) {               // RNE f32 -> bf16
    unsigned u = __float_as_uint(f);
    return (ushort_t)((u + 0x7fffu + ((u >> 16) & 1u)) >> 16);
}
__device__ inline float bfhi(unsigned x) { return __uint_as_float(x & 0xffff0000u); }
__device__ inline float bflo(unsigned x) { return __uint_as_float(x << 16); }

// =================== scan utilities ===================

__device__ inline int wave_incl_scan(int x, int lane) {
#pragma unroll
    for (int o = 1; o < 64; o <<= 1) { int y = __shfl_up(x, o, 64); if (lane >= o) x += y; }
    return x;
}

// 1024 elements per block (256 threads x 4); in-place safe
__global__ __launch_bounds__(256) void k_scan_a(const int* __restrict__ in, int* __restrict__ out,
                                                int* __restrict__ bsums, int n) {
    int t = threadIdx.x, lane = t & 63, wv = t >> 6;
    int base = blockIdx.x * 1024 + t * 4;
    int v[4]; int s = 0;
#pragma unroll
    for (int k = 0; k < 4; ++k) { int i = base + k; int x = (i < n) ? in[i] : 0; v[k] = s; s += x; }
    int incl = wave_incl_scan(s, lane);
    __shared__ int ws[4];
    if (lane == 63) ws[wv] = incl;
    __syncthreads();
    int wofs = 0;
#pragma unroll
    for (int w = 0; w < 4; ++w) if (w < wv) wofs += ws[w];
    int texcl = wofs + incl - s;
#pragma unroll
    for (int k = 0; k < 4; ++k) { int i = base + k; if (i < n) out[i] = texcl + v[k]; }
    if (t == 255) bsums[blockIdx.x] = wofs + incl;
}

// single-block exclusive scan over up to 2048 entries; in-place safe
__global__ __launch_bounds__(256) void k_scan_small(const int* __restrict__ cnt, int* __restrict__ ptr, int NB) {
    int t = threadIdx.x, lane = t & 63, wv = t >> 6;
    int base = t * 8;
    int local[8]; int s = 0;
#pragma unroll
    for (int k = 0; k < 8; ++k) { int i = base + k; int x = (i < NB) ? cnt[i] : 0; local[k] = s; s += x; }
    int incl = wave_incl_scan(s, lane);
    __shared__ int ws[4];
    if (lane == 63) ws[wv] = incl;
    __syncthreads();
    int wofs = 0;
#pragma unroll
    for (int w = 0; w < 4; ++w) if (w < wv) wofs += ws[w];
    int texcl = wofs + incl - s;
#pragma unroll
    for (int k = 0; k < 8; ++k) { int i = base + k; if (i < NB) ptr[i] = texcl + local[k]; }
}

// add block sums; also emit bucket pointers (bptr[b] = scanned hmat[b*NBLK], bptr[NB] = E)
__global__ __launch_bounds__(256) void k_scan_addb(int* __restrict__ data, const int* __restrict__ bsums,
                                                   int* __restrict__ bptr, int ntot, int E) {
    int i = blockIdx.x * 256 + threadIdx.x;
    if (i < ntot) {
        int v = data[i] + bsums[i >> 10];
        data[i] = v;
        if ((i & (NBLK - 1)) == 0) bptr[i / NBLK] = v;
    }
    if (i == 0) bptr[ntot / NBLK] = E;
}

// =================== contention-free bucket sort (bucket = dst >> 6) ===================

__global__ __launch_bounds__(256) void k_histA(const int* __restrict__ dst, int* __restrict__ hmat,
                                               int E, int NB, int chunk) {
    __shared__ int h[MAXNB];
    int blk = blockIdx.x;
    for (int i = threadIdx.x; i < NB; i += 256) h[i] = 0;
    __syncthreads();
    int beg = blk * chunk, end = beg + chunk; if (end > E) end = E;
    for (int e = beg + threadIdx.x; e < end; e += 256) atomicAdd(&h[dst[e] >> 6], 1);
    __syncthreads();
    for (int i = threadIdx.x; i < NB; i += 256) hmat[i * NBLK + blk] = h[i];
}

__global__ __launch_bounds__(256) void k_placeB(const int* __restrict__ src, const int* __restrict__ dst,
                                                const int* __restrict__ hmat, int* __restrict__ pairs,
                                                int E, int NB, int chunk) {
    __shared__ int cur[MAXNB];
    int blk = blockIdx.x;
    for (int i = threadIdx.x; i < NB; i += 256) cur[i] = hmat[i * NBLK + blk];
    __syncthreads();
    int beg = blk * chunk, end = beg + chunk; if (end > E) end = E;
    for (int e = beg + threadIdx.x; e < end; e += 256) {
        int s = src[e], d = dst[e];
        int off = atomicAdd(&cur[d >> 6], 1);
        pairs[off] = (s << 6) | (d & 63);
    }
}

// =================== fused node-level CSR: hist + 64-scan + row_ptr/cnt/dinv + place ===================
__global__ __launch_bounds__(256) void k_csr(const int* __restrict__ bptr, const int* __restrict__ pairs,
                                             int* __restrict__ row_ptr, int* __restrict__ cnt,
                                             float* __restrict__ dinv, int* __restrict__ col, int n) {
    __shared__ int h[64];
    __shared__ int cur[64];
    int b = blockIdx.x, t = threadIdx.x;
    if (t < 64) h[t] = 0;
    __syncthreads();
    int beg = bptr[b], end = bptr[b + 1];
    for (int j = beg + t; j < end; j += 256) atomicAdd(&h[pairs[j] & 63], 1);
    __syncthreads();
    if (t < 64) {
        int c = h[t];
        int ex = wave_incl_scan(c, t) - c;
        int node = (b << 6) + t;
        if (node < n) {
            row_ptr[node] = beg + ex;
            cnt[node] = c;
            dinv[node] = rsqrtf(1.0f + (float)c);
        }
        cur[t] = beg + ex;
    }
    __syncthreads();
    for (int j = beg + t; j < end; j += 256) {
        int pk = pairs[j];
        int p = atomicAdd(&cur[pk & 63], 1);
        col[p] = pk >> 6;
    }
}

// =================== register-blocked GEMM: LDS W + 16-deep k-step ===================
// hs[n][64](bf16) = (X @ W) * dinv[row].  Block: 64 rows x 64 cols. Thread: 4 rows x 4 cols.
// Per kb-step each thread issues 16 INDEPENDENT float4 x-loads (256 B in flight) before the
// 256 FMAs that consume them -> load latency amortized; W served from LDS (separate pipe).
template<int K>
__global__ __launch_bounds__(256, 4) void k_gemm(
    const float* __restrict__ X, const float* __restrict__ W,
    const float* __restrict__ dinv, ushort_t* __restrict__ out, int n)
{
    __shared__ float Ws[K * NF];
    int t = threadIdx.x;
    for (int i = t; i < K * NF / 4; i += 256) ((float4*)Ws)[i] = ((const float4*)W)[i];
    __syncthreads();

    int c0 = (t & 15) * 4;                       // 16 col-groups x 4 cols
    int row0 = blockIdx.x * 64 + (t >> 4) * 4;   // 16 row-groups x 4 rows

    const float* Xr[4];
#pragma unroll
    for (int r = 0; r < 4; ++r) {
        int row = row0 + r; if (row >= n) row = n - 1;   // clamp: dup loads, stores guarded
        Xr[r] = X + (size_t)row * K;
    }

    float4 acc[4];
#pragma unroll
    for (int r = 0; r < 4; ++r) acc[r] = make_float4(0.f, 0.f, 0.f, 0.f);

#pragma unroll 2
    for (int kb = 0; kb < K; kb += 16) {
        float4 xv[4][4];                         // 4 rows x 4 k-chunks, all independent loads
#pragma unroll
        for (int r = 0; r < 4; ++r)
#pragma unroll
            for (int q = 0; q < 4; ++q)
                xv[r][q] = *(const float4*)(Xr[r] + kb + q * 4);

#pragma unroll
        for (int q = 0; q < 4; ++q) {
#pragma unroll
            for (int kk = 0; kk < 4; ++kk) {
                float4 w = *(const float4*)(&Ws[(kb + q * 4 + kk) * NF + c0]);
#pragma unroll
                for (int r = 0; r < 4; ++r) {
                    float xs = ((const float*)&xv[r][q])[kk];
                    acc[r].x = fmaf(xs, w.x, acc[r].x);
                    acc[r].y = fmaf(xs, w.y, acc[r].y);
                    acc[r].z = fmaf(xs, w.z, acc[r].z);
                    acc[r].w = fmaf(xs, w.w, acc[r].w);
                }
            }
        }
    }

#pragma unroll
    for (int r = 0; r < 4; ++r) {
        int row = row0 + r;
        if (row < n) {
            float di = dinv[row];
            ushort4 o;
            o.x = f2bf(acc[r].x * di); o.y = f2bf(acc[r].y * di);
            o.z = f2bf(acc[r].z * di); o.w = f2bf(acc[r].w * di);
            *(ushort4*)(out + (size_t)row * NF + c0) = o;
        }
    }
}

// =================== pull aggregation: one 16-lane group per dst node, bf16 rows ===================
// r = relu( dinv[d] * (hs[d] + sum_{s in N(d)} hs[s]) + bias )
// DECODE=0: write r row (f32);  DECODE=1: write out[d] = r . Wd + bd
template<bool DECODE>
__global__ __launch_bounds__(256) void k_pull(
    const ushort_t* __restrict__ hs, const float* __restrict__ dinv,
    const int* __restrict__ row_ptr, const int* __restrict__ cnt,
    const int* __restrict__ col, const float* __restrict__ bias,
    const float* __restrict__ Wd, const float* __restrict__ bd,
    float* __restrict__ outv, int n)
{
    int d = blockIdx.x * 16 + (threadIdx.x >> 4);
    if (d >= n) return;
    int lt = threadIdx.x & 15;            // lane in group
    int fo = lt << 2;                     // feature offset (4 features/lane)
    int grpbase = threadIdx.x & 48;       // group base lane within wave
    int beg = row_ptr[d], deg = cnt[d];

    // self-loop (bf16 row, 8B/lane)
    uint2 sv = *((const uint2*)(hs + (size_t)d * NF) + lt);
    float4 acc = make_float4(bflo(sv.x), bfhi(sv.x), bflo(sv.y), bfhi(sv.y));

    for (int jb = 0; jb < deg; jb += 16) {
        int m = deg - jb; if (m > 16) m = 16;
        int idx = (lt < m) ? col[beg + jb + lt] : 0;
        uint2 v[16];
#pragma unroll
        for (int u = 0; u < 16; ++u) {
            int kk = (u < m) ? u : (m - 1);                  // clamp: dup loads hit L1
            int s = __shfl(idx, grpbase + kk, 64);
            v[u] = *((const uint2*)(hs + (size_t)s * NF) + lt);
        }
#pragma unroll
        for (int u = 0; u < 16; ++u) {
            if (u < m) {
                acc.x += bflo(v[u].x); acc.y += bfhi(v[u].x);
                acc.z += bflo(v[u].y); acc.w += bfhi(v[u].y);
            }
        }
    }

    float di = dinv[d];
    float4 bv = *(const float4*)(bias + fo);
    float rx = fmaxf(fmaf(acc.x, di, bv.x), 0.0f);
    float ry = fmaxf(fmaf(acc.y, di, bv.y), 0.0f);
    float rz = fmaxf(fmaf(acc.z, di, bv.z), 0.0f);
    float rw = fmaxf(fmaf(acc.w, di, bv.w), 0.0f);

    if (DECODE) {
        float4 wv = *(const float4*)(Wd + fo);
        float vsum = rx * wv.x + ry * wv.y + rz * wv.z + rw * wv.w;
#pragma unroll
        for (int o = 1; o < 16; o <<= 1) vsum += __shfl_xor(vsum, o, 64);
        if (lt == 0) outv[d] = vsum + bd[0];
    } else {
        *(float4*)(outv + (size_t)d * NF + fo) = make_float4(rx, ry, rz, rw);
    }
}

extern "C" void kernel_launch(void* const* d_in, const int* in_sizes, int n_in,
                              void* d_out, int out_size, void* d_ws, size_t ws_size,
                              hipStream_t stream) {
    const float* x  = (const float*)d_in[0];
    const int*   ei = (const int*)d_in[1];
    const float* W1 = (const float*)d_in[2];
    const float* b1 = (const float*)d_in[3];
    const float* W2 = (const float*)d_in[4];
    const float* b2 = (const float*)d_in[5];
    const float* Wd = (const float*)d_in[6];
    const float* bd = (const float*)d_in[7];
    float* out = (float*)d_out;

    int n = in_sizes[0] / 128;
    int E = in_sizes[1] / 2;
    const int* src = ei;
    const int* dst = ei + E;

    int NB = (n + 63) >> 6;                 // dst buckets of 64 nodes
    int chunk = (E + NBLK - 1) / NBLK;
    int ntot = NB * NBLK;                   // hist matrix size
    int nsb = (ntot + 1023) / 1024;         // scan blocks over hmat

    // workspace layout (4-byte elems) — pairs aliases bufH region (build ends before gemm1)
    float* dinv    = (float*)d_ws;                    // n
    float* bufH    = dinv + n;                        // 64n f32 region; used as bf16 (32n f32 worth)
    float* bufA    = bufH + (size_t)n * NF;           // 64n f32
    int*   counts  = (int*)(bufA + (size_t)n * NF);   // n
    int*   row_ptr = counts + n;                      // n
    int*   col     = row_ptr + n;                     // E
    int*   hmat    = col + E;                         // NB*NBLK
    int*   bptr    = hmat + ntot;                     // NB+1
    int*   bsums   = bptr + NB + 1;                   // <=1024
    int*   pairs   = (int*)bufH;                      // E (build lifetime only)
    ushort_t* hsb  = (ushort_t*)bufH;                 // 64n bf16 (post-build lifetime)

    // ---- bucket sort by dst (contention-free) ----
    k_histA<<<NBLK, 256, 0, stream>>>(dst, hmat, E, NB, chunk);
    k_scan_a<<<nsb, 256, 0, stream>>>(hmat, hmat, bsums, ntot);
    k_scan_small<<<1, 256, 0, stream>>>(bsums, bsums, nsb);
    k_scan_addb<<<(ntot + 255) / 256, 256, 0, stream>>>(hmat, bsums, bptr, ntot, E);
    k_placeB<<<NBLK, 256, 0, stream>>>(src, dst, hmat, pairs, E, NB, chunk);

    // ---- fused node-level CSR + dinv ----
    k_csr<<<NB, 256, 0, stream>>>(bptr, pairs, row_ptr, counts, dinv, col, n);

    // ---- layer 1: hs = bf16((x @ W1) * dinv) ; pull (+b1, relu) ----  (pairs dead from here)
    k_gemm<128><<<(n + 63) / 64, 256, 0, stream>>>(x, W1, dinv, hsb, n);
    k_pull<false><<<(n + 15) / 16, 256, 0, stream>>>(hsb, dinv, row_ptr, counts, col, b1,
                                                     Wd, bd, bufA, n);

    // ---- layer 2: hs = bf16((bufA @ W2) * dinv) ; pull (+b2, relu) + fused decode ----
    k_gemm<64><<<(n + 63) / 64, 256, 0, stream>>>(bufA, W2, dinv, hsb, n);
    k_pull<true><<<(n + 15) / 16, 256, 0, stream>>>(hsb, dinv, row_ptr, counts, col, b2,
                                                    Wd, bd, out, n);
}